// Round 3
// baseline (200.395 us; speedup 1.0000x reference)
//
#include <hip/hip_runtime.h>

// Fixed shapes: B=16, N=1024 contour pts (x,y); masks 16*512*512 f32.
constexpr int CN             = 1024;
constexpr int CONTOUR_BLOCKS = 256;   // 2 pairs * 16 batches * 8 rotation-slices
constexpr int MASK_BLOCKS    = 1024;
constexpr int THREADS        = 512;
constexpr int TOTAL_BLOCKS   = CONTOUR_BLOCKS + MASK_BLOCKS;

#define PHYS(k) ((k) + ((k) >> 4))   // LDS pad: breaks 128B-stride bank conflicts

// ws layout (floats):
//   wsmax[256]   : per (p,b,rslice) local max of circular correlation
//   wsS[64]      : per (p,b) {Sp, Sr}
//   wsm[5][1024] : per mask-block partials {s_gt, s_sm, s_cm, i_cg, i_cs}
//   cnt (u32)    : completed-block counter (memset to 0 each call)
__global__ __launch_bounds__(THREADS)
void fused_all(const float* __restrict__ gt_mask,
               const float* __restrict__ gt_contour,
               const float* __restrict__ snake_gt,
               const float* __restrict__ snake_classic,
               const float* __restrict__ snake_mask,
               const float* __restrict__ classic_contour,
               const float* __restrict__ classic_mask,
               float* __restrict__ wsmax,
               float* __restrict__ wsS,
               float* __restrict__ wsm,
               unsigned int* __restrict__ cnt,
               float* __restrict__ out)
{
    const int bid  = blockIdx.x;
    const int tid  = threadIdx.x;
    const int lane = tid & 63;
    const int wv   = tid >> 6;

    __shared__ float2 spred[1100];          // PHYS(1023)=1086
    __shared__ float2 sref[2200];           // PHYS(2048)=2176
    __shared__ float  corrW[8][128];        // per-wave partial corr (no atomics)
    __shared__ float  redA[8], redB[8], mxW[2];
    __shared__ float  mred[8][5];
    __shared__ double dredC[8][5];
    __shared__ float  segcons[2];
    __shared__ unsigned int sh_last;

    if (bid < CONTOUR_BLOCKS) {
        // ------- min_rotation_mse: corr for rotations [rs*128, rs*128+128) -------
        const int p  = bid >> 7;            // 0: (snake_GT, gt_contour) 1: (snake_classic, classic_contour)
        const int b  = (bid >> 3) & 15;
        const int rs = bid & 7;
        const float* pred = (p == 0 ? snake_gt   : snake_classic) + b * CN * 2;
        const float* ref  = (p == 0 ? gt_contour : classic_contour) + b * CN * 2;

        float4 pv = reinterpret_cast<const float4*>(pred)[tid];
        float4 rv = reinterpret_cast<const float4*>(ref)[tid];
        const int k0 = 2 * tid, k1 = 2 * tid + 1;
        spred[PHYS(k0)] = make_float2(pv.x, pv.y);
        spred[PHYS(k1)] = make_float2(pv.z, pv.w);
        float2 ra = make_float2(rv.x, rv.y), rb = make_float2(rv.z, rv.w);
        sref[PHYS(k0)]      = ra;  sref[PHYS(k1)]      = rb;
        sref[PHYS(k0 + CN)] = ra;  sref[PHYS(k1 + CN)] = rb;

        // Sp, Sr (rotation-invariant full sums)
        float sp = pv.x*pv.x + pv.y*pv.y + pv.z*pv.z + pv.w*pv.w;
        float sr = rv.x*rv.x + rv.y*rv.y + rv.z*rv.z + rv.w*rv.w;
        #pragma unroll
        for (int off = 32; off; off >>= 1) {
            sp += __shfl_down(sp, off);
            sr += __shfl_down(sr, off);
        }
        if (lane == 0) { redA[wv] = sp; redB[wv] = sr; }
        __syncthreads();

        // Thread: 16 rotations (rg) x 16 j (jg).
        const int rg    = tid & 7;
        const int jg    = tid >> 3;
        const int r0    = rs * 128 + rg * 16;
        const int jbase = jg * 16;
        const int K     = CN - r0;          // sref[j + K - ii] == ref[(j - (r0+ii)) mod N]

        float acc[16];
        #pragma unroll
        for (int i = 0; i < 16; ++i) acc[i] = 0.f;

        float2 w[16];                        // register sliding window, static indexing
        {
            const int base = jbase + K;
            #pragma unroll
            for (int i = 0; i < 16; ++i) w[i] = sref[PHYS(base - 15 + i)];
        }
        #pragma unroll
        for (int u = 0; u < 16; ++u) {
            const float2 pp = spred[PHYS(jbase + u)];
            #pragma unroll
            for (int ii = 0; ii < 16; ++ii) {
                const float2 wv2 = w[(u + 15 - ii) & 15];
                acc[ii] += pp.x * wv2.x;
                acc[ii] += pp.y * wv2.y;
            }
            w[u] = sref[PHYS(jbase + u + 1 + K)];
        }

        // Reduce over 8 j-subgroups (stride-8 lanes) -> lanes 0..7 hold full j-sums
        #pragma unroll
        for (int ii = 0; ii < 16; ++ii) {
            acc[ii] += __shfl_down(acc[ii], 32);
            acc[ii] += __shfl_down(acc[ii], 16);
            acc[ii] += __shfl_down(acc[ii], 8);
        }
        if (lane < 8) {
            #pragma unroll
            for (int ii = 0; ii < 16; ++ii) corrW[wv][lane * 16 + ii] = acc[ii];
        }
        __syncthreads();

        // Sum 8 wave-partials (fixed order) then max over 128 rotations
        if (tid < 128) {
            float s = corrW[0][tid];
            #pragma unroll
            for (int q = 1; q < 8; ++q) s += corrW[q][tid];
            #pragma unroll
            for (int off = 32; off; off >>= 1) s = fmaxf(s, __shfl_down(s, off));
            if (lane == 0) mxW[wv] = s;
        }
        __syncthreads();
        if (tid == 0) {
            wsmax[bid] = fmaxf(mxW[0], mxW[1]);
            if (rs == 0) {
                float Sp = 0.f, Sr = 0.f;
                #pragma unroll
                for (int i = 0; i < 8; ++i) { Sp += redA[i]; Sr += redB[i]; }
                wsS[(p * 16 + b) * 2]     = Sp;
                wsS[(p * 16 + b) * 2 + 1] = Sr;
            }
        }
    } else {
        // ---------------- fused mask sums (one pass over 3 arrays) ----------------
        const int mb = bid - CONTOUR_BLOCKS;
        const float4* g4 = reinterpret_cast<const float4*>(gt_mask);
        const float4* c4 = reinterpret_cast<const float4*>(classic_mask);
        const float4* s4 = reinterpret_cast<const float4*>(snake_mask);
        float s_gt = 0.f, s_sm = 0.f, s_cm = 0.f, i_cg = 0.f, i_cs = 0.f;
        #pragma unroll
        for (int pass = 0; pass < 2; ++pass) {
            const int idx = (pass * MASK_BLOCKS + mb) * THREADS + tid;  // coalesced
            const float4 g = g4[idx];
            const float4 c = c4[idx];
            const float4 s = s4[idx];
            s_gt += (g.x + g.y) + (g.z + g.w);
            s_sm += (s.x + s.y) + (s.z + s.w);
            s_cm += (c.x + c.y) + (c.z + c.w);
            i_cg += c.x*g.x + c.y*g.y + c.z*g.z + c.w*g.w;
            i_cs += c.x*s.x + c.y*s.y + c.z*s.z + c.w*s.w;
        }
        #pragma unroll
        for (int off = 32; off; off >>= 1) {
            s_gt += __shfl_down(s_gt, off);
            s_sm += __shfl_down(s_sm, off);
            s_cm += __shfl_down(s_cm, off);
            i_cg += __shfl_down(i_cg, off);
            i_cs += __shfl_down(i_cs, off);
        }
        if (lane == 0) {
            mred[wv][0] = s_gt; mred[wv][1] = s_sm; mred[wv][2] = s_cm;
            mred[wv][3] = i_cg; mred[wv][4] = i_cs;
        }
        __syncthreads();
        if (tid < 5) {
            float a = 0.f;
            #pragma unroll
            for (int i = 0; i < 8; ++i) a += mred[i][tid];
            wsm[tid * MASK_BLOCKS + mb] = a;   // non-atomic, deterministic
        }
    }

    // ---------------- last-block combine (replaces second kernel) ----------------
    __threadfence();                // release: make this block's ws writes device-visible
    __syncthreads();
    if (tid == 0) {
        unsigned int old = atomicAdd(cnt, 1u);
        sh_last = (old == (unsigned int)(TOTAL_BLOCKS - 1)) ? 1u : 0u;
    }
    __syncthreads();
    if (sh_last) {
        __threadfence();            // acquire: see all other blocks' partials

        // 5 mask sums, deterministic f64 tree
        double d[5];
        #pragma unroll
        for (int k = 0; k < 5; ++k)
            d[k] = (double)wsm[k * MASK_BLOCKS + tid]
                 + (double)wsm[k * MASK_BLOCKS + 512 + tid];
        #pragma unroll
        for (int off = 32; off; off >>= 1) {
            #pragma unroll
            for (int k = 0; k < 5; ++k) d[k] += __shfl_down(d[k], off);
        }
        if (lane == 0) {
            #pragma unroll
            for (int k = 0; k < 5; ++k) dredC[wv][k] = d[k];
        }

        // per-(p,b) min-mse from rotation-slice maxima (wave 0)
        if (wv == 0) {
            float vseg = 0.f, vcon = 0.f;
            if (tid < 32) {
                float M = wsmax[tid * 8];
                #pragma unroll
                for (int i = 1; i < 8; ++i) M = fmaxf(M, wsmax[tid * 8 + i]);
                const float mse = (wsS[2 * tid] + wsS[2 * tid + 1] - 2.f * M) * (1.f / (2.f * CN));
                if (tid < 16) vseg = mse; else vcon = mse;
            }
            #pragma unroll
            for (int off = 32; off; off >>= 1) {
                vseg += __shfl_down(vseg, off);
                vcon += __shfl_down(vcon, off);
            }
            if (lane == 0) { segcons[0] = vseg; segcons[1] = vcon; }
        }
        __syncthreads();

        if (tid == 0) {
            double s[5] = {0, 0, 0, 0, 0};
            for (int q = 0; q < 8; ++q)
                for (int k = 0; k < 5; ++k) s[k] += dredC[q][k];
            const double s_gt = s[0], s_sm = s[1], s_cm = s[2], i_cg = s[3], i_cs = s[4];
            const double dice1 = 1.0 - (2.0 * i_cg + 1.0) / (s_cm + s_gt + 1.0);
            const double dice2 = 1.0 - (2.0 * i_cs + 1.0) / (s_cm + s_sm + 1.0);
            out[0] = (float)(dice1 + (double)segcons[0] + 0.5 * (dice2 + (double)segcons[1]));
        }
    }
}

extern "C" void kernel_launch(void* const* d_in, const int* in_sizes, int n_in,
                              void* d_out, int out_size, void* d_ws, size_t ws_size,
                              hipStream_t stream)
{
    const float* gt_mask         = (const float*)d_in[0];
    const float* gt_contour      = (const float*)d_in[1];
    const float* snake_gt        = (const float*)d_in[2];
    const float* snake_classic   = (const float*)d_in[3];
    const float* snake_mask      = (const float*)d_in[4];
    const float* classic_contour = (const float*)d_in[5];
    const float* classic_mask    = (const float*)d_in[6];

    float* wsmax = (float*)d_ws;                          // 256
    float* wsS   = wsmax + CONTOUR_BLOCKS;                // 64
    float* wsm   = wsS + 64;                              // 5 * 1024
    unsigned int* cnt = (unsigned int*)(wsm + 5 * MASK_BLOCKS);

    hipMemsetAsync(cnt, 0, sizeof(unsigned int), stream); // counter only

    fused_all<<<TOTAL_BLOCKS, THREADS, 0, stream>>>(
        gt_mask, gt_contour, snake_gt, snake_classic,
        snake_mask, classic_contour, classic_mask,
        wsmax, wsS, wsm, cnt, (float*)d_out);
}

// Round 4
// 22.242 us; speedup vs baseline: 9.0096x; 9.0096x over previous
//
#include <hip/hip_runtime.h>

// Fixed shapes: B=16, N=1024 contour pts (x,y); masks 16*512*512 f32.
constexpr int CN             = 1024;
constexpr int MASK_BLOCKS    = 512;   // dispatched first: bid in [0, 512)
constexpr int CONTOUR_BLOCKS = 256;   // bid in [512, 768): 2 pairs * 16 batches * 8 rot-slices
constexpr int THREADS        = 512;

#define PHYS(k) ((k) + ((k) >> 4))   // LDS pad: breaks 128B-stride bank conflicts

// ws layout (floats):
//   wsmax[256]  : per (p,b,rslice) local max of circular correlation
//   wsS[64]     : per (p,b) {Sp, Sr}
//   wsm[5][512] : per mask-block partials {s_gt, s_sm, s_cm, i_cg, i_cs}
__global__ __launch_bounds__(THREADS)
void fused_main(const float* __restrict__ gt_mask,
                const float* __restrict__ gt_contour,
                const float* __restrict__ snake_gt,
                const float* __restrict__ snake_classic,
                const float* __restrict__ snake_mask,
                const float* __restrict__ classic_contour,
                const float* __restrict__ classic_mask,
                float* __restrict__ wsmax,
                float* __restrict__ wsS,
                float* __restrict__ wsm)
{
    const int bid  = blockIdx.x;
    const int tid  = threadIdx.x;
    const int lane = tid & 63;
    const int wv   = tid >> 6;

    __shared__ float2 spred[1100];          // PHYS(1023)=1086
    __shared__ float2 sref[2200];           // PHYS(2048)=2176
    __shared__ float  corrW[8][128];        // per-wave partial corr (no atomics)
    __shared__ float  redA[8], redB[8], mxW[2];
    __shared__ float  mred[8][5];

    if (bid < MASK_BLOCKS) {
        // ---------------- fused mask sums: 12 independent float4 loads in flight ----
        const float4* g4 = reinterpret_cast<const float4*>(gt_mask);
        const float4* c4 = reinterpret_cast<const float4*>(classic_mask);
        const float4* s4 = reinterpret_cast<const float4*>(snake_mask);
        float s_gt = 0.f, s_sm = 0.f, s_cm = 0.f, i_cg = 0.f, i_cs = 0.f;
        #pragma unroll
        for (int pass = 0; pass < 4; ++pass) {
            const int idx = (pass * MASK_BLOCKS + bid) * THREADS + tid;  // coalesced
            const float4 g = g4[idx];
            const float4 c = c4[idx];
            const float4 s = s4[idx];
            s_gt += (g.x + g.y) + (g.z + g.w);
            s_sm += (s.x + s.y) + (s.z + s.w);
            s_cm += (c.x + c.y) + (c.z + c.w);
            i_cg += c.x*g.x + c.y*g.y + c.z*g.z + c.w*g.w;
            i_cs += c.x*s.x + c.y*s.y + c.z*s.z + c.w*s.w;
        }
        #pragma unroll
        for (int off = 32; off; off >>= 1) {
            s_gt += __shfl_down(s_gt, off);
            s_sm += __shfl_down(s_sm, off);
            s_cm += __shfl_down(s_cm, off);
            i_cg += __shfl_down(i_cg, off);
            i_cs += __shfl_down(i_cs, off);
        }
        if (lane == 0) {
            mred[wv][0] = s_gt; mred[wv][1] = s_sm; mred[wv][2] = s_cm;
            mred[wv][3] = i_cg; mred[wv][4] = i_cs;
        }
        __syncthreads();
        if (tid < 5) {
            float a = 0.f;
            #pragma unroll
            for (int i = 0; i < 8; ++i) a += mred[i][tid];
            wsm[tid * MASK_BLOCKS + bid] = a;   // non-atomic, deterministic
        }
    } else {
        // ------- min_rotation_mse: corr for rotations [rs*128, rs*128+128) -------
        const int cb = bid - MASK_BLOCKS;
        const int p  = cb >> 7;             // 0: (snake_GT, gt_contour) 1: (snake_classic, classic_contour)
        const int b  = (cb >> 3) & 15;
        const int rs = cb & 7;
        const float* pred = (p == 0 ? snake_gt   : snake_classic) + b * CN * 2;
        const float* ref  = (p == 0 ? gt_contour : classic_contour) + b * CN * 2;

        float4 pv = reinterpret_cast<const float4*>(pred)[tid];
        float4 rv = reinterpret_cast<const float4*>(ref)[tid];
        const int k0 = 2 * tid, k1 = 2 * tid + 1;
        spred[PHYS(k0)] = make_float2(pv.x, pv.y);
        spred[PHYS(k1)] = make_float2(pv.z, pv.w);
        float2 ra = make_float2(rv.x, rv.y), rb = make_float2(rv.z, rv.w);
        sref[PHYS(k0)]      = ra;  sref[PHYS(k1)]      = rb;
        sref[PHYS(k0 + CN)] = ra;  sref[PHYS(k1 + CN)] = rb;

        // Sp, Sr (rotation-invariant full sums)
        float sp = pv.x*pv.x + pv.y*pv.y + pv.z*pv.z + pv.w*pv.w;
        float sr = rv.x*rv.x + rv.y*rv.y + rv.z*rv.z + rv.w*rv.w;
        #pragma unroll
        for (int off = 32; off; off >>= 1) {
            sp += __shfl_down(sp, off);
            sr += __shfl_down(sr, off);
        }
        if (lane == 0) { redA[wv] = sp; redB[wv] = sr; }
        __syncthreads();

        // Thread: 16 rotations (rg) x 16 j (jg).
        const int rg    = tid & 7;
        const int jg    = tid >> 3;
        const int r0    = rs * 128 + rg * 16;
        const int jbase = jg * 16;
        const int K     = CN - r0;          // sref[j + K - ii] == ref[(j - (r0+ii)) mod N]

        float acc[16];
        #pragma unroll
        for (int i = 0; i < 16; ++i) acc[i] = 0.f;

        float2 w[16];                        // register sliding window, static indexing
        {
            const int base = jbase + K;
            #pragma unroll
            for (int i = 0; i < 16; ++i) w[i] = sref[PHYS(base - 15 + i)];
        }
        #pragma unroll
        for (int u = 0; u < 16; ++u) {
            const float2 pp = spred[PHYS(jbase + u)];
            #pragma unroll
            for (int ii = 0; ii < 16; ++ii) {
                const float2 wv2 = w[(u + 15 - ii) & 15];
                acc[ii] += pp.x * wv2.x;
                acc[ii] += pp.y * wv2.y;
            }
            w[u] = sref[PHYS(jbase + u + 1 + K)];
        }

        // Reduce over 8 j-subgroups (stride-8 lanes) -> lanes 0..7 hold full j-sums
        #pragma unroll
        for (int ii = 0; ii < 16; ++ii) {
            acc[ii] += __shfl_down(acc[ii], 32);
            acc[ii] += __shfl_down(acc[ii], 16);
            acc[ii] += __shfl_down(acc[ii], 8);
        }
        if (lane < 8) {
            #pragma unroll
            for (int ii = 0; ii < 16; ++ii) corrW[wv][lane * 16 + ii] = acc[ii];
        }
        __syncthreads();

        // Sum 8 wave-partials (fixed order) then max over 128 rotations
        if (tid < 128) {
            float s = corrW[0][tid];
            #pragma unroll
            for (int q = 1; q < 8; ++q) s += corrW[q][tid];
            #pragma unroll
            for (int off = 32; off; off >>= 1) s = fmaxf(s, __shfl_down(s, off));
            if (lane == 0) mxW[wv] = s;
        }
        __syncthreads();
        if (tid == 0) {
            wsmax[cb] = fmaxf(mxW[0], mxW[1]);
            if (rs == 0) {
                float Sp = 0.f, Sr = 0.f;
                #pragma unroll
                for (int i = 0; i < 8; ++i) { Sp += redA[i]; Sr += redB[i]; }
                wsS[(p * 16 + b) * 2]     = Sp;
                wsS[(p * 16 + b) * 2 + 1] = Sr;
            }
        }
    }
}

__global__ __launch_bounds__(THREADS)
void combine_kernel(const float* __restrict__ wsmax,
                    const float* __restrict__ wsS,
                    const float* __restrict__ wsm,
                    float* __restrict__ out)
{
    const int t = threadIdx.x, lane = t & 63, wv = t >> 6;
    __shared__ double dred[8][5];
    __shared__ float  segcons[2];

    double d[5];
    #pragma unroll
    for (int k = 0; k < 5; ++k) d[k] = (double)wsm[k * MASK_BLOCKS + t];
    #pragma unroll
    for (int off = 32; off; off >>= 1) {
        #pragma unroll
        for (int k = 0; k < 5; ++k) d[k] += __shfl_down(d[k], off);
    }
    if (lane == 0) {
        #pragma unroll
        for (int k = 0; k < 5; ++k) dred[wv][k] = d[k];
    }

    if (wv == 0) {
        float vseg = 0.f, vcon = 0.f;
        if (t < 32) {
            float M = wsmax[t * 8];
            #pragma unroll
            for (int i = 1; i < 8; ++i) M = fmaxf(M, wsmax[t * 8 + i]);
            const float mse = (wsS[2 * t] + wsS[2 * t + 1] - 2.f * M) * (1.f / (2.f * CN));
            if (t < 16) vseg = mse; else vcon = mse;
        }
        #pragma unroll
        for (int off = 32; off; off >>= 1) {
            vseg += __shfl_down(vseg, off);
            vcon += __shfl_down(vcon, off);
        }
        if (lane == 0) { segcons[0] = vseg; segcons[1] = vcon; }
    }
    __syncthreads();

    if (t == 0) {
        double s[5] = {0, 0, 0, 0, 0};
        for (int q = 0; q < 8; ++q)
            for (int k = 0; k < 5; ++k) s[k] += dred[q][k];
        const double s_gt = s[0], s_sm = s[1], s_cm = s[2], i_cg = s[3], i_cs = s[4];
        const double dice1 = 1.0 - (2.0 * i_cg + 1.0) / (s_cm + s_gt + 1.0);
        const double dice2 = 1.0 - (2.0 * i_cs + 1.0) / (s_cm + s_sm + 1.0);
        out[0] = (float)(dice1 + (double)segcons[0] + 0.5 * (dice2 + (double)segcons[1]));
    }
}

extern "C" void kernel_launch(void* const* d_in, const int* in_sizes, int n_in,
                              void* d_out, int out_size, void* d_ws, size_t ws_size,
                              hipStream_t stream)
{
    const float* gt_mask         = (const float*)d_in[0];
    const float* gt_contour      = (const float*)d_in[1];
    const float* snake_gt        = (const float*)d_in[2];
    const float* snake_classic   = (const float*)d_in[3];
    const float* snake_mask      = (const float*)d_in[4];
    const float* classic_contour = (const float*)d_in[5];
    const float* classic_mask    = (const float*)d_in[6];

    float* wsmax = (float*)d_ws;                 // 256
    float* wsS   = wsmax + CONTOUR_BLOCKS;       // 64
    float* wsm   = wsS + 64;                     // 5 * 512

    fused_main<<<MASK_BLOCKS + CONTOUR_BLOCKS, THREADS, 0, stream>>>(
        gt_mask, gt_contour, snake_gt, snake_classic,
        snake_mask, classic_contour, classic_mask, wsmax, wsS, wsm);

    combine_kernel<<<1, THREADS, 0, stream>>>(wsmax, wsS, wsm, (float*)d_out);
}